// Round 1
// 318.023 us; speedup vs baseline: 1.0071x; 1.0071x over previous
//
#include <hip/hip_runtime.h>
#include <cstdint>
#include <cmath>

// Problem constants
constexpr int TT   = 256;   // tokens
constexpr int HD   = 1024;  // hidden
constexpr int IDIM = 512;   // intermediate
constexpr int NE   = 32;    // experts
constexpr int NGRP = 8;
constexpr int TKG  = 4;
constexpr int TOPK = 8;
constexpr float RSCALE = 2.5f;

constexpr int NSX  = HD / 32;     // 32 k-slabs in Xe
constexpr int NSA  = IDIM / 32;   // 16 k-slabs in A
constexpr int SLAB = 16 * 64 * 8; // halves per (expert, slab): 16 mt-tiles x 64 lanes x 8

typedef float    f32x4 __attribute__((ext_vector_type(4)));
typedef _Float16 half8 __attribute__((ext_vector_type(8)));

// Workspace layout (bytes)
constexpr size_t WS_CNT = 0;                              // NE ints (zeroed)
constexpr size_t WS_TOK = 256;                            // NE*TT ints
constexpr size_t WS_WL  = WS_TOK + (size_t)NE * TT * 4;   // NE*TT floats
constexpr size_t WS_XE  = WS_WL  + (size_t)NE * TT * 4;   // NE*NSX*SLAB f16 (16 MB), frag-swizzled x
constexpr size_t WS_A   = WS_XE  + (size_t)NE * NSX * SLAB * 2; // NE*NSA*SLAB f16 (8 MB)

// ---------------- Routing (unchanged) ----------------
__global__ __launch_bounds__(256) void k_route(
    const float* __restrict__ x, const float* __restrict__ gw,
    const float* __restrict__ bias, int* __restrict__ cnt,
    int* __restrict__ tok, float* __restrict__ wl)
{
    int t = blockIdx.x;
    int tid = threadIdx.x;
    int e2 = (tid & 15) * 2;
    int c  = tid >> 4;
    const float* xr = x + (size_t)t * HD;

    float a0 = 0.f, a1 = 0.f;
    int h0 = c * (HD / 16);
#pragma unroll 8
    for (int h = h0; h < h0 + HD / 16; ++h) {
        float xv = xr[h];
        float2 wv = *(const float2*)&gw[(size_t)h * NE + e2];
        a0 += xv * wv.x;
        a1 += xv * wv.y;
    }

    __shared__ float part[16][NE];
    part[c][e2]     = a0;
    part[c][e2 + 1] = a1;
    __syncthreads();

    __shared__ float sc[NE], sfc[NE];
    if (tid < NE) {
        float s = 0.f;
#pragma unroll
        for (int cc = 0; cc < 16; ++cc) s += part[cc][tid];
        float sig = 1.f / (1.f + expf(-s));
        sc[tid]  = sig;
        sfc[tid] = sig + bias[tid];
    }
    __syncthreads();

    if (tid == 0) {
        float gs[NGRP];
        for (int g = 0; g < NGRP; ++g) {
            float m1 = -3.0e38f, m2 = -3.0e38f;
            for (int j = 0; j < 4; ++j) {
                float v = sfc[4 * g + j];
                if (v > m1) { m2 = m1; m1 = v; } else if (v > m2) m2 = v;
            }
            gs[g] = m1 + m2;
        }
        bool gsel[NGRP];
        for (int g = 0; g < NGRP; ++g) gsel[g] = false;
        for (int r = 0; r < TKG; ++r) {
            int bi = -1; float bv = -3.0e38f;
            for (int g = 0; g < NGRP; ++g)
                if (!gsel[g] && gs[g] > bv) { bv = gs[g]; bi = g; }
            gsel[bi] = true;
        }
        float masked[NE];
        for (int i = 0; i < NE; ++i) masked[i] = gsel[i >> 2] ? sfc[i] : 0.0f;
        int   idx[TOPK]; float wv[TOPK]; float wsum = 0.f;
        for (int r = 0; r < TOPK; ++r) {
            int bi = -1; float bv = -3.0e38f;
            for (int i = 0; i < NE; ++i)
                if (masked[i] > bv) { bv = masked[i]; bi = i; }
            masked[bi] = -3.0e38f;
            idx[r] = bi; wv[r] = sc[bi]; wsum += wv[r];
        }
        float inv = RSCALE / (wsum + 1e-20f);
        for (int r = 0; r < TOPK; ++r) {
            int ee = idx[r];
            int pos = atomicAdd(&cnt[ee], 1);
            tok[(size_t)ee * TT + pos] = t;
            wl [(size_t)ee * TT + pos] = wv[r] * inv;
        }
    }
}

// ---------------- Pack: gather x rows into MFMA-A-fragment slabs ----------------
// 1-D grid, XCD-swizzled so expert e lives on XCD e>>2 (same map as gateup/down).
__global__ __launch_bounds__(256) void k_pack(
    const float* __restrict__ x, const int* __restrict__ cnt,
    const int* __restrict__ tok, _Float16* __restrict__ Xe)
{
    int bid  = blockIdx.x;
    int xcd  = bid & 7;
    int slot = bid >> 3;            // 0..127
    int e    = xcd * 4 + (slot & 3);
    int s    = slot >> 2;           // 0..31
    int n_e = cnt[e];
    if (n_e == 0) return;
    int tid = threadIdx.x, w = tid >> 6, lane = tid & 63;
    int m16 = lane & 15, q = lane >> 4;
    _Float16* base = Xe + ((size_t)e * NSX + s) * SLAB;
#pragma unroll
    for (int k = 0; k < 4; ++k) {
        int mt = w + k * 4;
        int slot2 = mt * 16 + m16;
        if (slot2 >= n_e) slot2 = n_e - 1;   // clamp: dup of last row (finite garbage)
        int t = tok[e * TT + slot2];
        const float* src = x + (size_t)t * HD + s * 32 + q * 8;
        f32x4 v0 = *(const f32x4*)src;
        f32x4 v1 = *(const f32x4*)(src + 4);
        half8 h;
        h[0] = (_Float16)v0.x; h[1] = (_Float16)v0.y; h[2] = (_Float16)v0.z; h[3] = (_Float16)v0.w;
        h[4] = (_Float16)v1.x; h[5] = (_Float16)v1.y; h[6] = (_Float16)v1.z; h[7] = (_Float16)v1.w;
        *(half8*)(base + ((size_t)mt * 64 + lane) * 8) = h;
    }
}

// ---------------- Gate/Up ----------------
// 1-D grid NE*2*(IDIM/16) = 2048, 64-thread blocks; tile 128 tokens x 16 cols.
// No LDS: the weight load pattern IS the B-fragment layout (lane (m16,q) loads
// W[k=q*8+j][i0+m16]) — convert f32->f16 in registers and feed MFMA directly.
// Register pipeline: A-fragments 3-deep, weights 4-deep.
__global__ __launch_bounds__(64) void k_gateup(
    const _Float16* __restrict__ Xe, const float* __restrict__ Wg,
    const float* __restrict__ Wu, const int* __restrict__ cnt,
    _Float16* __restrict__ A)
{
    int bid  = blockIdx.x;
    int xcd  = bid & 7;
    int slot = bid >> 3;            // 0..255
    int e    = xcd * 4 + (slot & 3);
    int rest = slot >> 2;           // 0..63
    int ttile = rest & 1;
    int iy    = rest >> 1;          // 0..31
    int n_e = cnt[e];
    if (ttile * 128 >= n_e) return;
    int mtbase = ttile * 8;
    int i0 = iy * 16;
    int lane = threadIdx.x;
    int m16 = lane & 15, q = lane >> 4;

    const _Float16* abase = Xe + (size_t)e * NSX * SLAB + ((size_t)mtbase * 64 + lane) * 8;
    const float* gp = Wg + ((size_t)e * HD + q * 8) * IDIM + i0 + m16;
    const float* up = Wu + ((size_t)e * HD + q * 8) * IDIM + i0 + m16;

    f32x4 accG[8], accU[8];
#pragma unroll
    for (int mt = 0; mt < 8; ++mt) {
        accG[mt] = (f32x4){0.f, 0.f, 0.f, 0.f};
        accU[mt] = (f32x4){0.f, 0.f, 0.f, 0.f};
    }

    half8 af[3][8];
    float wg[4][8], wu[4][8];

#define GU_ISSUE_A(KS, AB)                                                     \
    { const _Float16* a_ = abase + (size_t)(KS) * SLAB;                        \
      _Pragma("unroll")                                                        \
      for (int mt_ = 0; mt_ < 8; ++mt_)                                        \
          af[AB][mt_] = *(const half8*)(a_ + mt_ * 512); }

#define GU_ISSUE_W(KS, ST)                                                     \
    { const float* g_ = gp + (size_t)(KS) * 32 * IDIM;                         \
      const float* u_ = up + (size_t)(KS) * 32 * IDIM;                         \
      _Pragma("unroll")                                                        \
      for (int j_ = 0; j_ < 8; ++j_) {                                         \
          wg[ST][j_] = g_[(size_t)j_ * IDIM];                                  \
          wu[ST][j_] = u_[(size_t)j_ * IDIM];                                  \
      } }

    GU_ISSUE_A(0, 0)
    GU_ISSUE_A(1, 1)
    GU_ISSUE_W(0, 0) GU_ISSUE_W(1, 1) GU_ISSUE_W(2, 2) GU_ISSUE_W(3, 3)

    constexpr int NK = HD / 32;   // 32
#pragma unroll
    for (int ks = 0; ks < NK; ++ks) {
        const int ab = ks % 3;        // compile-time after full unroll
        const int st = ks & 3;
        // prefetch A two steps ahead into the free buffer (issued before MFMAs)
        if (ks + 2 < NK) GU_ISSUE_A(ks + 2, (ks + 2) % 3)
        // convert this step's weights (frees wg[st]/wu[st] for re-issue)
        half8 bg, bu;
#pragma unroll
        for (int j = 0; j < 8; ++j) {
            bg[j] = (_Float16)wg[st][j];
            bu[j] = (_Float16)wu[st][j];
        }
        // prefetch weights four steps ahead (issue before the MFMA cluster)
        if (ks + 4 < NK) GU_ISSUE_W(ks + 4, st)
#pragma unroll
        for (int mt = 0; mt < 8; ++mt) {
            accG[mt] = __builtin_amdgcn_mfma_f32_16x16x32_f16(af[ab][mt], bg, accG[mt], 0, 0, 0);
            accU[mt] = __builtin_amdgcn_mfma_f32_16x16x32_f16(af[ab][mt], bu, accU[mt], 0, 0, 0);
        }
    }
#undef GU_ISSUE_A
#undef GU_ISSUE_W

    // store silu(g)*u into A in A-fragment slab order (for k_down's A-operand)
    _Float16* aout = A + ((size_t)e * NSA + (iy >> 1)) * SLAB;
    int cj   = m16 & 7;
    int lsub = ((iy * 2 + (m16 >> 3)) & 3) * 16;
#pragma unroll
    for (int mt = 0; mt < 8; ++mt) {
#pragma unroll
        for (int r = 0; r < 4; ++r) {
            float g = accG[mt][r], u = accU[mt][r];
            float a = (g / (1.f + expf(-g))) * u;
            int lp = (q * 4 + r) + lsub;
            aout[((size_t)(mtbase + mt) * 64 + lp) * 8 + cj] = (_Float16)a;
        }
    }
}

// ---------------- Down ----------------
// 1-D grid NE*2*(HD/16) = 4096, 64-thread blocks; tile 128 tokens x 16 cols.
__global__ __launch_bounds__(64) void k_down(
    const _Float16* __restrict__ A, const float* __restrict__ Wd,
    const int* __restrict__ cnt, const int* __restrict__ tok,
    const float* __restrict__ wl, float* __restrict__ outf)
{
    int bid  = blockIdx.x;
    int xcd  = bid & 7;
    int slot = bid >> 3;            // 0..511
    int e    = xcd * 4 + (slot & 3);
    int rest = slot >> 2;           // 0..127
    int ttile = rest & 1;
    int hy    = rest >> 1;          // 0..63
    int n_e = cnt[e];
    if (ttile * 128 >= n_e) return;
    int mtbase = ttile * 8;
    int h0 = hy * 16;
    int lane = threadIdx.x;
    int m16 = lane & 15, q = lane >> 4;

    const _Float16* abase = A + (size_t)e * NSA * SLAB + ((size_t)mtbase * 64 + lane) * 8;
    const float* dp = Wd + ((size_t)e * IDIM + q * 8) * HD + h0 + m16;

    f32x4 acc[8];
#pragma unroll
    for (int mt = 0; mt < 8; ++mt) acc[mt] = (f32x4){0.f, 0.f, 0.f, 0.f};

    half8 af[3][8];
    float wd[4][8];

#define DN_ISSUE_A(KS, AB)                                                     \
    { const _Float16* a_ = abase + (size_t)(KS) * SLAB;                        \
      _Pragma("unroll")                                                        \
      for (int mt_ = 0; mt_ < 8; ++mt_)                                        \
          af[AB][mt_] = *(const half8*)(a_ + mt_ * 512); }

#define DN_ISSUE_W(KS, ST)                                                     \
    { const float* d_ = dp + (size_t)(KS) * 32 * HD;                           \
      _Pragma("unroll")                                                        \
      for (int j_ = 0; j_ < 8; ++j_) wd[ST][j_] = d_[(size_t)j_ * HD]; }

    DN_ISSUE_A(0, 0)
    DN_ISSUE_A(1, 1)
    DN_ISSUE_W(0, 0) DN_ISSUE_W(1, 1) DN_ISSUE_W(2, 2) DN_ISSUE_W(3, 3)

    constexpr int NK = IDIM / 32;  // 16
#pragma unroll
    for (int ks = 0; ks < NK; ++ks) {
        const int ab = ks % 3;
        const int st = ks & 3;
        if (ks + 2 < NK) DN_ISSUE_A(ks + 2, (ks + 2) % 3)
        half8 bd;
#pragma unroll
        for (int j = 0; j < 8; ++j) bd[j] = (_Float16)wd[st][j];
        if (ks + 4 < NK) DN_ISSUE_W(ks + 4, st)
#pragma unroll
        for (int mt = 0; mt < 8; ++mt)
            acc[mt] = __builtin_amdgcn_mfma_f32_16x16x32_f16(af[ab][mt], bd, acc[mt], 0, 0, 0);
    }
#undef DN_ISSUE_A
#undef DN_ISSUE_W

    int col = h0 + m16;
#pragma unroll
    for (int mt = 0; mt < 8; ++mt) {
#pragma unroll
        for (int r = 0; r < 4; ++r) {
            int slot2 = ttile * 128 + mt * 16 + q * 4 + r;
            if (slot2 < n_e) {
                int t   = tok[(size_t)e * TT + slot2];
                float wt = wl[(size_t)e * TT + slot2];
                atomicAdd(&outf[(size_t)t * HD + col], wt * acc[mt][r]);
            }
        }
    }
}

extern "C" void kernel_launch(void* const* d_in, const int* in_sizes, int n_in,
                              void* d_out, int out_size, void* d_ws, size_t ws_size,
                              hipStream_t stream) {
    const float* x    = (const float*)d_in[0];
    const float* gw   = (const float*)d_in[1];
    const float* bias = (const float*)d_in[2];
    const float* Wg   = (const float*)d_in[3];
    const float* Wu   = (const float*)d_in[4];
    const float* Wd   = (const float*)d_in[5];
    float* out = (float*)d_out;   // reference output dtype is float32

    char* ws = (char*)d_ws;
    int*      cnt = (int*)(ws + WS_CNT);
    int*      tok = (int*)(ws + WS_TOK);
    float*    wl  = (float*)(ws + WS_WL);
    _Float16* Xe  = (_Float16*)(ws + WS_XE);
    _Float16* A   = (_Float16*)(ws + WS_A);

    hipMemsetAsync(ws, 0, 256, stream);                       // expert counters
    hipMemsetAsync(out, 0, (size_t)TT * HD * 4, stream);      // f32 output accumulator

    k_route<<<TT, 256, 0, stream>>>(x, gw, bias, cnt, tok, wl);
    k_pack<<<NE * NSX, 256, 0, stream>>>(x, cnt, tok, Xe);
    k_gateup<<<NE * 2 * (IDIM / 16), 64, 0, stream>>>(Xe, Wg, Wu, cnt, A);
    k_down<<<NE * 2 * (HD / 16), 64, 0, stream>>>(A, Wd, cnt, tok, wl, out);
}

// Round 2
// 290.072 us; speedup vs baseline: 1.1041x; 1.0964x over previous
//
#include <hip/hip_runtime.h>
#include <cstdint>
#include <cmath>

// Problem constants
constexpr int TT   = 256;   // tokens
constexpr int HD   = 1024;  // hidden
constexpr int IDIM = 512;   // intermediate
constexpr int NE   = 32;    // experts
constexpr int NGRP = 8;
constexpr int TKG  = 4;
constexpr int TOPK = 8;
constexpr float RSCALE = 2.5f;

constexpr int NSX  = HD / 32;     // 32 k-slabs in Xe
constexpr int NSA  = IDIM / 32;   // 16 k-slabs in A
constexpr int SLAB = 16 * 64 * 8; // halves per (expert, slab): 16 mt-tiles x 64 lanes x 8

typedef float    f32x4 __attribute__((ext_vector_type(4)));
typedef _Float16 half8 __attribute__((ext_vector_type(8)));

// Workspace layout (bytes)
constexpr size_t WS_CNT = 0;                              // NE ints (zeroed)
constexpr size_t WS_TOK = 256;                            // NE*TT ints
constexpr size_t WS_WL  = WS_TOK + (size_t)NE * TT * 4;   // NE*TT floats
constexpr size_t WS_XE  = WS_WL  + (size_t)NE * TT * 4;   // NE*NSX*SLAB f16 (16 MB), frag-swizzled x
constexpr size_t WS_A   = WS_XE  + (size_t)NE * NSX * SLAB * 2; // NE*NSA*SLAB f16 (8 MB)

// global->LDS direct staging, 16B per lane (dest = wave-uniform base + lane*16)
#define GLOAD16(GP, LP) __builtin_amdgcn_global_load_lds(                      \
    (const __attribute__((address_space(1))) unsigned int*)(GP),               \
    (__attribute__((address_space(3))) unsigned int*)(LP), 16, 0, 0)

// ---------------- Routing (unchanged) ----------------
__global__ __launch_bounds__(256) void k_route(
    const float* __restrict__ x, const float* __restrict__ gw,
    const float* __restrict__ bias, int* __restrict__ cnt,
    int* __restrict__ tok, float* __restrict__ wl)
{
    int t = blockIdx.x;
    int tid = threadIdx.x;
    int e2 = (tid & 15) * 2;
    int c  = tid >> 4;
    const float* xr = x + (size_t)t * HD;

    float a0 = 0.f, a1 = 0.f;
    int h0 = c * (HD / 16);
#pragma unroll 8
    for (int h = h0; h < h0 + HD / 16; ++h) {
        float xv = xr[h];
        float2 wv = *(const float2*)&gw[(size_t)h * NE + e2];
        a0 += xv * wv.x;
        a1 += xv * wv.y;
    }

    __shared__ float part[16][NE];
    part[c][e2]     = a0;
    part[c][e2 + 1] = a1;
    __syncthreads();

    __shared__ float sc[NE], sfc[NE];
    if (tid < NE) {
        float s = 0.f;
#pragma unroll
        for (int cc = 0; cc < 16; ++cc) s += part[cc][tid];
        float sig = 1.f / (1.f + expf(-s));
        sc[tid]  = sig;
        sfc[tid] = sig + bias[tid];
    }
    __syncthreads();

    if (tid == 0) {
        float gs[NGRP];
        for (int g = 0; g < NGRP; ++g) {
            float m1 = -3.0e38f, m2 = -3.0e38f;
            for (int j = 0; j < 4; ++j) {
                float v = sfc[4 * g + j];
                if (v > m1) { m2 = m1; m1 = v; } else if (v > m2) m2 = v;
            }
            gs[g] = m1 + m2;
        }
        bool gsel[NGRP];
        for (int g = 0; g < NGRP; ++g) gsel[g] = false;
        for (int r = 0; r < TKG; ++r) {
            int bi = -1; float bv = -3.0e38f;
            for (int g = 0; g < NGRP; ++g)
                if (!gsel[g] && gs[g] > bv) { bv = gs[g]; bi = g; }
            gsel[bi] = true;
        }
        float masked[NE];
        for (int i = 0; i < NE; ++i) masked[i] = gsel[i >> 2] ? sfc[i] : 0.0f;
        int   idx[TOPK]; float wv[TOPK]; float wsum = 0.f;
        for (int r = 0; r < TOPK; ++r) {
            int bi = -1; float bv = -3.0e38f;
            for (int i = 0; i < NE; ++i)
                if (masked[i] > bv) { bv = masked[i]; bi = i; }
            masked[bi] = -3.0e38f;
            idx[r] = bi; wv[r] = sc[bi]; wsum += wv[r];
        }
        float inv = RSCALE / (wsum + 1e-20f);
        for (int r = 0; r < TOPK; ++r) {
            int ee = idx[r];
            int pos = atomicAdd(&cnt[ee], 1);
            tok[(size_t)ee * TT + pos] = t;
            wl [(size_t)ee * TT + pos] = wv[r] * inv;
        }
    }
}

// ---------------- Pack: gather x rows into MFMA-A-fragment slabs ----------------
__global__ __launch_bounds__(256) void k_pack(
    const float* __restrict__ x, const int* __restrict__ cnt,
    const int* __restrict__ tok, _Float16* __restrict__ Xe)
{
    int bid  = blockIdx.x;
    int xcd  = bid & 7;
    int slot = bid >> 3;            // 0..127
    int e    = xcd * 4 + (slot & 3);
    int s    = slot >> 2;           // 0..31
    int n_e = cnt[e];
    if (n_e == 0) return;
    int tid = threadIdx.x, w = tid >> 6, lane = tid & 63;
    int m16 = lane & 15, q = lane >> 4;
    _Float16* base = Xe + ((size_t)e * NSX + s) * SLAB;
#pragma unroll
    for (int k = 0; k < 4; ++k) {
        int mt = w + k * 4;
        int slot2 = mt * 16 + m16;
        if (slot2 >= n_e) slot2 = n_e - 1;   // clamp: dup of last row (finite garbage)
        int t = tok[e * TT + slot2];
        const float* src = x + (size_t)t * HD + s * 32 + q * 8;
        f32x4 v0 = *(const f32x4*)src;
        f32x4 v1 = *(const f32x4*)(src + 4);
        half8 h;
        h[0] = (_Float16)v0.x; h[1] = (_Float16)v0.y; h[2] = (_Float16)v0.z; h[3] = (_Float16)v0.w;
        h[4] = (_Float16)v1.x; h[5] = (_Float16)v1.y; h[6] = (_Float16)v1.z; h[7] = (_Float16)v1.w;
        *(half8*)(base + ((size_t)mt * 64 + lane) * 8) = h;
    }
}

// ---------------- Gate/Up ----------------
// 1024 blocks (XCD-swizzled: expert e on XCD e>>2), 128 threads = 2 waves.
// Block tile: 128 tokens x 32 cols. Per k-step (32 k): stage Wg/Wu 32x32 f32
// tiles to LDS via global_load_lds (coalesced dwordx4, HW-pipelined, compiler
// cannot sink), double-buffered 2-phase; A-fragments register-direct from Xe
// (L2-resident). Col^16 XOR swizzle on LDS content kills ds_read bank
// conflicts (both-sides swizzle: pre-swizzled global source + swizzled read).
__global__ __launch_bounds__(128) void k_gateup(
    const _Float16* __restrict__ Xe, const float* __restrict__ Wg,
    const float* __restrict__ Wu, const int* __restrict__ cnt,
    _Float16* __restrict__ A)
{
    int bid  = blockIdx.x;
    int xcd  = bid & 7;
    int slot = bid >> 3;            // 0..127
    int e    = xcd * 4 + (slot & 3);
    int rest = slot >> 2;           // 0..31
    int ttile = rest & 1;
    int ig    = rest >> 1;          // 0..15 (32-col groups)
    int n_e = cnt[e];
    if (ttile * 128 >= n_e) return;
    int mtbase = ttile * 8;
    int i0 = ig * 32;
    int tid  = threadIdx.x;
    int w    = tid >> 6;            // wave 0/1 -> cols i0 + w*16 .. +15
    int lane = tid & 63;
    int m16 = lane & 15, q = lane >> 4;
    int wcol = w * 16 + m16;

    __shared__ __align__(16) float LG[2][32][32];
    __shared__ __align__(16) float LU[2][32][32];

    const _Float16* abase = Xe + (size_t)e * NSX * SLAB + ((size_t)mtbase * 64 + lane) * 8;
    const float* gw0 = Wg + (size_t)e * HD * IDIM + i0;
    const float* uw0 = Wu + (size_t)e * HD * IDIM + i0;

    f32x4 accG[8], accU[8];
#pragma unroll
    for (int mt = 0; mt < 8; ++mt) {
        accG[mt] = (f32x4){0.f, 0.f, 0.f, 0.f};
        accU[mt] = (f32x4){0.f, 0.f, 0.f, 0.f};
    }

    half8 af0[8], af1[8];

    // stage one 32x32 f32 tile pair for k-step KS into buffer B.
    // chunk c = 1 KB (8 rows); wave w issues chunks {2w, 2w+1} per matrix.
    // content swizzle: LDS[row][col] = W[row][col ^ (((row>>3)&1)<<4)];
    // for chunk c, (row>>3) == c, so the XOR bit is (c&1) — uniform per issue.
#define GU_STAGE(B, KS)                                                        \
    { _Pragma("unroll")                                                        \
      for (int ci = 0; ci < 2; ++ci) {                                         \
        int c    = w * 2 + ci;                                                 \
        int row  = c * 8 + (lane >> 3);                                        \
        int csrc = ((lane & 7) << 2) ^ ((c & 1) << 4);                         \
        const float* gs = gw0 + ((size_t)(KS) * 32 + row) * IDIM + csrc;       \
        const float* us = uw0 + ((size_t)(KS) * 32 + row) * IDIM + csrc;       \
        GLOAD16(gs, &LG[B][c * 8][0]);                                         \
        GLOAD16(us, &LU[B][c * 8][0]);                                         \
      } }

#define GU_LOADA(KS, AF)                                                       \
    { const _Float16* a_ = abase + (size_t)(KS) * SLAB;                        \
      _Pragma("unroll")                                                        \
      for (int mt_ = 0; mt_ < 8; ++mt_) AF[mt_] = *(const half8*)(a_ + mt_ * 512); }

    // fragment read: lane (m16,q) needs W[k=q*8+j][wcol]; stored col is
    // wcol ^ ((q&1)<<4) (since (k>>3)&1 == q&1 for j<8) -> 2-way banks (free).
#define GU_COMPUTE(B, AF)                                                      \
    { int lc = wcol ^ ((q & 1) << 4);                                          \
      half8 bg, bu;                                                            \
      _Pragma("unroll")                                                        \
      for (int j_ = 0; j_ < 8; ++j_) {                                         \
        bg[j_] = (_Float16)LG[B][q * 8 + j_][lc];                              \
        bu[j_] = (_Float16)LU[B][q * 8 + j_][lc];                              \
      }                                                                        \
      _Pragma("unroll")                                                        \
      for (int mt_ = 0; mt_ < 8; ++mt_) {                                      \
        accG[mt_] = __builtin_amdgcn_mfma_f32_16x16x32_f16(AF[mt_], bg, accG[mt_], 0, 0, 0); \
        accU[mt_] = __builtin_amdgcn_mfma_f32_16x16x32_f16(AF[mt_], bu, accU[mt_], 0, 0, 0); \
      } }

    constexpr int NK = HD / 32;   // 32 (even)
    GU_STAGE(0, 0)
    GU_LOADA(0, af0)
    __syncthreads();

    for (int ks = 0; ks < NK; ks += 2) {
        // even phase: stage ks+1 into buf1, compute ks from buf0
        GU_STAGE(1, ks + 1)
        GU_LOADA(ks + 1, af1)
        GU_COMPUTE(0, af0)
        __syncthreads();
        // odd phase: stage ks+2 into buf0, compute ks+1 from buf1
        if (ks + 2 < NK) { GU_STAGE(0, ks + 2) GU_LOADA(ks + 2, af0) }
        GU_COMPUTE(1, af1)
        __syncthreads();
    }
#undef GU_STAGE
#undef GU_LOADA
#undef GU_COMPUTE

    // store silu(g)*u into A in A-fragment slab order (for k_down's A-operand)
    int iyw = ig * 2 + w;                       // 16-col tile index 0..31
    _Float16* aout = A + ((size_t)e * NSA + (iyw >> 1)) * SLAB;
    int cj   = m16 & 7;
    int lsub = ((iyw * 2 + (m16 >> 3)) & 3) * 16;
#pragma unroll
    for (int mt = 0; mt < 8; ++mt) {
#pragma unroll
        for (int r = 0; r < 4; ++r) {
            float g = accG[mt][r], u = accU[mt][r];
            float a = (g / (1.f + expf(-g))) * u;
            int lp = (q * 4 + r) + lsub;
            aout[((size_t)(mtbase + mt) * 64 + lp) * 8 + cj] = (_Float16)a;
        }
    }
}

// ---------------- Down ----------------
// 2048 blocks (XCD-swizzled), 128 threads = 2 waves; tile 128 tokens x 32 cols.
__global__ __launch_bounds__(128) void k_down(
    const _Float16* __restrict__ A, const float* __restrict__ Wd,
    const int* __restrict__ cnt, const int* __restrict__ tok,
    const float* __restrict__ wl, float* __restrict__ outf)
{
    int bid  = blockIdx.x;
    int xcd  = bid & 7;
    int slot = bid >> 3;            // 0..255
    int e    = xcd * 4 + (slot & 3);
    int rest = slot >> 2;           // 0..63
    int ttile = rest & 1;
    int hg    = rest >> 1;          // 0..31 (32-col groups)
    int n_e = cnt[e];
    if (ttile * 128 >= n_e) return;
    int mtbase = ttile * 8;
    int h0 = hg * 32;
    int tid  = threadIdx.x;
    int w    = tid >> 6;
    int lane = tid & 63;
    int m16 = lane & 15, q = lane >> 4;
    int wcol = w * 16 + m16;

    __shared__ __align__(16) float LD[2][32][32];

    const _Float16* abase = A + (size_t)e * NSA * SLAB + ((size_t)mtbase * 64 + lane) * 8;
    const float* dw0 = Wd + (size_t)e * IDIM * HD + h0;

    f32x4 acc[8];
#pragma unroll
    for (int mt = 0; mt < 8; ++mt) acc[mt] = (f32x4){0.f, 0.f, 0.f, 0.f};

    half8 af0[8], af1[8];

#define DN_STAGE(B, KS)                                                        \
    { _Pragma("unroll")                                                        \
      for (int ci = 0; ci < 2; ++ci) {                                         \
        int c    = w * 2 + ci;                                                 \
        int row  = c * 8 + (lane >> 3);                                        \
        int csrc = ((lane & 7) << 2) ^ ((c & 1) << 4);                         \
        const float* ds = dw0 + ((size_t)(KS) * 32 + row) * HD + csrc;         \
        GLOAD16(ds, &LD[B][c * 8][0]);                                         \
      } }

#define DN_LOADA(KS, AF)                                                       \
    { const _Float16* a_ = abase + (size_t)(KS) * SLAB;                        \
      _Pragma("unroll")                                                        \
      for (int mt_ = 0; mt_ < 8; ++mt_) AF[mt_] = *(const half8*)(a_ + mt_ * 512); }

#define DN_COMPUTE(B, AF)                                                      \
    { int lc = wcol ^ ((q & 1) << 4);                                          \
      half8 bd;                                                                \
      _Pragma("unroll")                                                        \
      for (int j_ = 0; j_ < 8; ++j_) bd[j_] = (_Float16)LD[B][q * 8 + j_][lc]; \
      _Pragma("unroll")                                                        \
      for (int mt_ = 0; mt_ < 8; ++mt_)                                        \
        acc[mt_] = __builtin_amdgcn_mfma_f32_16x16x32_f16(AF[mt_], bd, acc[mt_], 0, 0, 0); }

    constexpr int NK = IDIM / 32;  // 16 (even)
    DN_STAGE(0, 0)
    DN_LOADA(0, af0)
    __syncthreads();

    for (int ks = 0; ks < NK; ks += 2) {
        DN_STAGE(1, ks + 1)
        DN_LOADA(ks + 1, af1)
        DN_COMPUTE(0, af0)
        __syncthreads();
        if (ks + 2 < NK) { DN_STAGE(0, ks + 2) DN_LOADA(ks + 2, af0) }
        DN_COMPUTE(1, af1)
        __syncthreads();
    }
#undef DN_STAGE
#undef DN_LOADA
#undef DN_COMPUTE

    int col = h0 + w * 16 + m16;
#pragma unroll
    for (int mt = 0; mt < 8; ++mt) {
#pragma unroll
        for (int r = 0; r < 4; ++r) {
            int slot2 = ttile * 128 + mt * 16 + q * 4 + r;
            if (slot2 < n_e) {
                int t   = tok[(size_t)e * TT + slot2];
                float wt = wl[(size_t)e * TT + slot2];
                atomicAdd(&outf[(size_t)t * HD + col], wt * acc[mt][r]);
            }
        }
    }
}

extern "C" void kernel_launch(void* const* d_in, const int* in_sizes, int n_in,
                              void* d_out, int out_size, void* d_ws, size_t ws_size,
                              hipStream_t stream) {
    const float* x    = (const float*)d_in[0];
    const float* gw   = (const float*)d_in[1];
    const float* bias = (const float*)d_in[2];
    const float* Wg   = (const float*)d_in[3];
    const float* Wu   = (const float*)d_in[4];
    const float* Wd   = (const float*)d_in[5];
    float* out = (float*)d_out;   // reference output dtype is float32

    char* ws = (char*)d_ws;
    int*      cnt = (int*)(ws + WS_CNT);
    int*      tok = (int*)(ws + WS_TOK);
    float*    wl  = (float*)(ws + WS_WL);
    _Float16* Xe  = (_Float16*)(ws + WS_XE);
    _Float16* A   = (_Float16*)(ws + WS_A);

    hipMemsetAsync(ws, 0, 256, stream);                       // expert counters
    hipMemsetAsync(out, 0, (size_t)TT * HD * 4, stream);      // f32 output accumulator

    k_route<<<TT, 256, 0, stream>>>(x, gw, bias, cnt, tok, wl);
    k_pack<<<NE * NSX, 256, 0, stream>>>(x, cnt, tok, Xe);
    k_gateup<<<NE * 2 * (IDIM / 32), 128, 0, stream>>>(Xe, Wg, Wu, cnt, A);
    k_down<<<NE * 2 * (HD / 32), 128, 0, stream>>>(A, Wd, cnt, tok, wl, out);
}

// Round 3
// 276.379 us; speedup vs baseline: 1.1588x; 1.0495x over previous
//
#include <hip/hip_runtime.h>
#include <cstdint>
#include <cmath>

// Problem constants
constexpr int TT   = 256;   // tokens
constexpr int HD   = 1024;  // hidden
constexpr int IDIM = 512;   // intermediate
constexpr int NE   = 32;    // experts
constexpr int NGRP = 8;
constexpr int TKG  = 4;
constexpr int TOPK = 8;
constexpr float RSCALE = 2.5f;

constexpr int NSX  = HD / 32;     // 32 k-slabs in Xe
constexpr int NSA  = IDIM / 32;   // 16 k-slabs in A
constexpr int SLAB = 16 * 64 * 8; // halves per (expert, slab): 16 mt-tiles x 64 lanes x 8

typedef float    f32x4 __attribute__((ext_vector_type(4)));
typedef _Float16 half8 __attribute__((ext_vector_type(8)));

// Workspace layout (bytes)
constexpr size_t WS_CNT = 0;                              // NE ints (zeroed)
constexpr size_t WS_TOK = 256;                            // NE*TT ints
constexpr size_t WS_WL  = WS_TOK + (size_t)NE * TT * 4;   // NE*TT floats
constexpr size_t WS_XE  = WS_WL  + (size_t)NE * TT * 4;   // NE*NSX*SLAB f16 (16 MB), frag-swizzled x
constexpr size_t WS_A   = WS_XE  + (size_t)NE * NSX * SLAB * 2; // NE*NSA*SLAB f16 (8 MB)

// global->LDS direct staging, 16B per lane (dest = wave-uniform base + lane*16)
#define GLOAD16(GP, LP) __builtin_amdgcn_global_load_lds(                      \
    (const __attribute__((address_space(1))) unsigned int*)(GP),               \
    (__attribute__((address_space(3))) unsigned int*)(LP), 16, 0, 0)

// counted vmcnt wait: pins surrounding memory ops (issue-order anchors) and
// waits until at most N VMEM ops are outstanding. NEVER 0 in the main loop.
#define WAITVM(N) asm volatile("s_waitcnt vmcnt(" #N ")" ::: "memory")

// ---------------- Routing (unchanged) ----------------
__global__ __launch_bounds__(256) void k_route(
    const float* __restrict__ x, const float* __restrict__ gw,
    const float* __restrict__ bias, int* __restrict__ cnt,
    int* __restrict__ tok, float* __restrict__ wl)
{
    int t = blockIdx.x;
    int tid = threadIdx.x;
    int e2 = (tid & 15) * 2;
    int c  = tid >> 4;
    const float* xr = x + (size_t)t * HD;

    float a0 = 0.f, a1 = 0.f;
    int h0 = c * (HD / 16);
#pragma unroll 8
    for (int h = h0; h < h0 + HD / 16; ++h) {
        float xv = xr[h];
        float2 wv = *(const float2*)&gw[(size_t)h * NE + e2];
        a0 += xv * wv.x;
        a1 += xv * wv.y;
    }

    __shared__ float part[16][NE];
    part[c][e2]     = a0;
    part[c][e2 + 1] = a1;
    __syncthreads();

    __shared__ float sc[NE], sfc[NE];
    if (tid < NE) {
        float s = 0.f;
#pragma unroll
        for (int cc = 0; cc < 16; ++cc) s += part[cc][tid];
        float sig = 1.f / (1.f + expf(-s));
        sc[tid]  = sig;
        sfc[tid] = sig + bias[tid];
    }
    __syncthreads();

    if (tid == 0) {
        float gs[NGRP];
        for (int g = 0; g < NGRP; ++g) {
            float m1 = -3.0e38f, m2 = -3.0e38f;
            for (int j = 0; j < 4; ++j) {
                float v = sfc[4 * g + j];
                if (v > m1) { m2 = m1; m1 = v; } else if (v > m2) m2 = v;
            }
            gs[g] = m1 + m2;
        }
        bool gsel[NGRP];
        for (int g = 0; g < NGRP; ++g) gsel[g] = false;
        for (int r = 0; r < TKG; ++r) {
            int bi = -1; float bv = -3.0e38f;
            for (int g = 0; g < NGRP; ++g)
                if (!gsel[g] && gs[g] > bv) { bv = gs[g]; bi = g; }
            gsel[bi] = true;
        }
        float masked[NE];
        for (int i = 0; i < NE; ++i) masked[i] = gsel[i >> 2] ? sfc[i] : 0.0f;
        int   idx[TOPK]; float wv[TOPK]; float wsum = 0.f;
        for (int r = 0; r < TOPK; ++r) {
            int bi = -1; float bv = -3.0e38f;
            for (int i = 0; i < NE; ++i)
                if (masked[i] > bv) { bv = masked[i]; bi = i; }
            masked[bi] = -3.0e38f;
            idx[r] = bi; wv[r] = sc[bi]; wsum += wv[r];
        }
        float inv = RSCALE / (wsum + 1e-20f);
        for (int r = 0; r < TOPK; ++r) {
            int ee = idx[r];
            int pos = atomicAdd(&cnt[ee], 1);
            tok[(size_t)ee * TT + pos] = t;
            wl [(size_t)ee * TT + pos] = wv[r] * inv;
        }
    }
}

// ---------------- Pack: gather x rows into MFMA-A-fragment slabs ----------------
__global__ __launch_bounds__(256) void k_pack(
    const float* __restrict__ x, const int* __restrict__ cnt,
    const int* __restrict__ tok, _Float16* __restrict__ Xe)
{
    int bid  = blockIdx.x;
    int xcd  = bid & 7;
    int slot = bid >> 3;            // 0..127
    int e    = xcd * 4 + (slot & 3);
    int s    = slot >> 2;           // 0..31
    int n_e = cnt[e];
    if (n_e == 0) return;
    int tid = threadIdx.x, w = tid >> 6, lane = tid & 63;
    int m16 = lane & 15, q = lane >> 4;
    _Float16* base = Xe + ((size_t)e * NSX + s) * SLAB;
#pragma unroll
    for (int k = 0; k < 4; ++k) {
        int mt = w + k * 4;
        int slot2 = mt * 16 + m16;
        if (slot2 >= n_e) slot2 = n_e - 1;   // clamp: dup of last row (finite garbage)
        int t = tok[e * TT + slot2];
        const float* src = x + (size_t)t * HD + s * 32 + q * 8;
        f32x4 v0 = *(const f32x4*)src;
        f32x4 v1 = *(const f32x4*)(src + 4);
        half8 h;
        h[0] = (_Float16)v0.x; h[1] = (_Float16)v0.y; h[2] = (_Float16)v0.z; h[3] = (_Float16)v0.w;
        h[4] = (_Float16)v1.x; h[5] = (_Float16)v1.y; h[6] = (_Float16)v1.z; h[7] = (_Float16)v1.w;
        *(half8*)(base + ((size_t)mt * 64 + lane) * 8) = h;
    }
}

// ---------------- Gate/Up ----------------
// 1024 blocks (XCD-swizzled), 128 threads = 2 waves; tile 128 tokens x 32 cols.
// Deep pipeline: weight tiles staged via global_load_lds into 6 LDS buffers,
// 4 steps ahead; A-fragments 3-deep in VGPRs, 2 steps ahead. Raw s_barrier +
// counted vmcnt (steady 24 = 2 weight-stages + 2 A-loads in flight) — never
// drain to 0 in the loop. Full unroll keeps all indices/immediates static.
__global__ __launch_bounds__(128, 1) void k_gateup(
    const _Float16* __restrict__ Xe, const float* __restrict__ Wg,
    const float* __restrict__ Wu, const int* __restrict__ cnt,
    _Float16* __restrict__ A)
{
    int bid  = blockIdx.x;
    int xcd  = bid & 7;
    int slot = bid >> 3;            // 0..127
    int e    = xcd * 4 + (slot & 3);
    int rest = slot >> 2;           // 0..31
    int ttile = rest & 1;
    int ig    = rest >> 1;          // 0..15 (32-col groups)
    int n_e = cnt[e];
    if (ttile * 128 >= n_e) return;
    int mtbase = ttile * 8;
    int i0 = ig * 32;
    int tid  = threadIdx.x;
    int w    = tid >> 6;            // wave 0/1 -> cols i0 + w*16 .. +15
    int lane = tid & 63;
    int m16 = lane & 15, q = lane >> 4;
    int wcol = w * 16 + m16;

    __shared__ __align__(16) float LG[6][32][32];
    __shared__ __align__(16) float LU[6][32][32];

    const _Float16* abase = Xe + (size_t)e * NSX * SLAB + ((size_t)mtbase * 64 + lane) * 8;
    const float* gw0 = Wg + (size_t)e * HD * IDIM + i0;
    const float* uw0 = Wu + (size_t)e * HD * IDIM + i0;

    f32x4 accG[8], accU[8];
#pragma unroll
    for (int mt = 0; mt < 8; ++mt) {
        accG[mt] = (f32x4){0.f, 0.f, 0.f, 0.f};
        accU[mt] = (f32x4){0.f, 0.f, 0.f, 0.f};
    }

    half8 af[3][8];

    // stage one 32x32 f32 tile pair for k-step KS into buffer B (4 gloads/wave).
    // content swizzle: LDS[row][col] = W[row][col ^ (((row>>3)&1)<<4)].
#define GU_STAGE(B, KS)                                                        \
    { _Pragma("unroll")                                                        \
      for (int ci = 0; ci < 2; ++ci) {                                         \
        int c    = w * 2 + ci;                                                 \
        int row  = c * 8 + (lane >> 3);                                        \
        int csrc = ((lane & 7) << 2) ^ ((c & 1) << 4);                         \
        const float* gs = gw0 + ((size_t)(KS) * 32 + row) * IDIM + csrc;       \
        const float* us = uw0 + ((size_t)(KS) * 32 + row) * IDIM + csrc;       \
        GLOAD16(gs, &LG[B][c * 8][0]);                                         \
        GLOAD16(us, &LU[B][c * 8][0]);                                         \
      } }

#define GU_LOADA(KS, AF)                                                       \
    { const _Float16* a_ = abase + (size_t)(KS) * SLAB;                        \
      _Pragma("unroll")                                                        \
      for (int mt_ = 0; mt_ < 8; ++mt_) AF[mt_] = *(const half8*)(a_ + mt_ * 512); }

    // fragment read: lane (m16,q) needs W[k=q*8+j][wcol]; stored col is
    // wcol ^ ((q&1)<<4) -> 2-way banks (free).
#define GU_COMPUTE(B, AF)                                                      \
    { int lc = wcol ^ ((q & 1) << 4);                                          \
      half8 bg, bu;                                                            \
      _Pragma("unroll")                                                        \
      for (int j_ = 0; j_ < 8; ++j_) {                                         \
        bg[j_] = (_Float16)LG[B][q * 8 + j_][lc];                              \
        bu[j_] = (_Float16)LU[B][q * 8 + j_][lc];                              \
      }                                                                        \
      _Pragma("unroll")                                                        \
      for (int mt_ = 0; mt_ < 8; ++mt_) {                                      \
        accG[mt_] = __builtin_amdgcn_mfma_f32_16x16x32_f16(AF[mt_], bg, accG[mt_], 0, 0, 0); \
        accU[mt_] = __builtin_amdgcn_mfma_f32_16x16x32_f16(AF[mt_], bu, accU[mt_], 0, 0, 0); \
      } }

    constexpr int NK = HD / 32;   // 32
    // prologue: weights 4 steps deep, A-frags 2 steps deep
    GU_STAGE(0, 0) GU_STAGE(1, 1) GU_STAGE(2, 2) GU_STAGE(3, 3)
    GU_LOADA(0, af[0]) GU_LOADA(1, af[1])

#pragma unroll
    for (int ks = 0; ks < NK; ++ks) {
        if (ks + 4 < NK) GU_STAGE((ks + 4) % 6, ks + 4)
        if (ks + 2 < NK) GU_LOADA(ks + 2, af[(ks + 2) % 3])
        if      (ks == 0)      { WAITVM(20); }
        else if (ks + 5 <= NK) { WAITVM(24); }
        else if (ks + 4 == NK) { WAITVM(20); }
        else if (ks + 3 == NK) { WAITVM(16); }
        else if (ks + 2 == NK) { WAITVM(8);  }
        else                   { WAITVM(0);  }
        __builtin_amdgcn_s_barrier();
        __builtin_amdgcn_sched_barrier(0);
        GU_COMPUTE(ks % 6, af[ks % 3])
    }
#undef GU_STAGE
#undef GU_LOADA
#undef GU_COMPUTE

    // store silu(g)*u into A in A-fragment slab order (for k_down's A-operand)
    int iyw = ig * 2 + w;                       // 16-col tile index 0..31
    _Float16* aout = A + ((size_t)e * NSA + (iyw >> 1)) * SLAB;
    int cj   = m16 & 7;
    int lsub = ((iyw * 2 + (m16 >> 3)) & 3) * 16;
#pragma unroll
    for (int mt = 0; mt < 8; ++mt) {
#pragma unroll
        for (int r = 0; r < 4; ++r) {
            float g = accG[mt][r], u = accU[mt][r];
            float a = (g / (1.f + expf(-g))) * u;
            int lp = (q * 4 + r) + lsub;
            aout[((size_t)(mtbase + mt) * 64 + lp) * 8 + cj] = (_Float16)a;
        }
    }
}

// ---------------- Down ----------------
// 2048 blocks (XCD-swizzled), 128 threads = 2 waves; tile 128 tokens x 32 cols.
// Same deep-pipeline structure as k_gateup (NK=16).
__global__ __launch_bounds__(128, 1) void k_down(
    const _Float16* __restrict__ A, const float* __restrict__ Wd,
    const int* __restrict__ cnt, const int* __restrict__ tok,
    const float* __restrict__ wl, float* __restrict__ outf)
{
    int bid  = blockIdx.x;
    int xcd  = bid & 7;
    int slot = bid >> 3;            // 0..255
    int e    = xcd * 4 + (slot & 3);
    int rest = slot >> 2;           // 0..63
    int ttile = rest & 1;
    int hg    = rest >> 1;          // 0..31 (32-col groups)
    int n_e = cnt[e];
    if (ttile * 128 >= n_e) return;
    int mtbase = ttile * 8;
    int h0 = hg * 32;
    int tid  = threadIdx.x;
    int w    = tid >> 6;
    int lane = tid & 63;
    int m16 = lane & 15, q = lane >> 4;
    int wcol = w * 16 + m16;

    __shared__ __align__(16) float LD[6][32][32];

    const _Float16* abase = A + (size_t)e * NSA * SLAB + ((size_t)mtbase * 64 + lane) * 8;
    const float* dw0 = Wd + (size_t)e * IDIM * HD + h0;

    f32x4 acc[8];
#pragma unroll
    for (int mt = 0; mt < 8; ++mt) acc[mt] = (f32x4){0.f, 0.f, 0.f, 0.f};

    half8 af[3][8];

#define DN_STAGE(B, KS)                                                        \
    { _Pragma("unroll")                                                        \
      for (int ci = 0; ci < 2; ++ci) {                                         \
        int c    = w * 2 + ci;                                                 \
        int row  = c * 8 + (lane >> 3);                                        \
        int csrc = ((lane & 7) << 2) ^ ((c & 1) << 4);                         \
        const float* ds = dw0 + ((size_t)(KS) * 32 + row) * HD + csrc;         \
        GLOAD16(ds, &LD[B][c * 8][0]);                                         \
      } }

#define DN_LOADA(KS, AF)                                                       \
    { const _Float16* a_ = abase + (size_t)(KS) * SLAB;                        \
      _Pragma("unroll")                                                        \
      for (int mt_ = 0; mt_ < 8; ++mt_) AF[mt_] = *(const half8*)(a_ + mt_ * 512); }

#define DN_COMPUTE(B, AF)                                                      \
    { int lc = wcol ^ ((q & 1) << 4);                                          \
      half8 bd;                                                                \
      _Pragma("unroll")                                                        \
      for (int j_ = 0; j_ < 8; ++j_) bd[j_] = (_Float16)LD[B][q * 8 + j_][lc]; \
      _Pragma("unroll")                                                        \
      for (int mt_ = 0; mt_ < 8; ++mt_)                                        \
        acc[mt_] = __builtin_amdgcn_mfma_f32_16x16x32_f16(AF[mt_], bd, acc[mt_], 0, 0, 0); }

    constexpr int NK = IDIM / 32;  // 16
    DN_STAGE(0, 0) DN_STAGE(1, 1) DN_STAGE(2, 2) DN_STAGE(3, 3)
    DN_LOADA(0, af[0]) DN_LOADA(1, af[1])

    // per-step issue for down: 2 gloads (one matrix) + 8 A-loads -> steady
    // wait = g(k+3),g(k+4) [2+2] + A(k+1),A(k+2) [8+8] = 20
#pragma unroll
    for (int ks = 0; ks < NK; ++ks) {
        if (ks + 4 < NK) DN_STAGE((ks + 4) % 6, ks + 4)
        if (ks + 2 < NK) DN_LOADA(ks + 2, af[(ks + 2) % 3])
        if      (ks == 0)      { WAITVM(18); }
        else if (ks + 5 <= NK) { WAITVM(20); }
        else if (ks + 4 == NK) { WAITVM(18); }
        else if (ks + 3 == NK) { WAITVM(16); }
        else if (ks + 2 == NK) { WAITVM(8);  }
        else                   { WAITVM(0);  }
        __builtin_amdgcn_s_barrier();
        __builtin_amdgcn_sched_barrier(0);
        DN_COMPUTE(ks % 6, af[ks % 3])
    }
#undef DN_STAGE
#undef DN_LOADA
#undef DN_COMPUTE

    int col = h0 + w * 16 + m16;
#pragma unroll
    for (int mt = 0; mt < 8; ++mt) {
#pragma unroll
        for (int r = 0; r < 4; ++r) {
            int slot2 = ttile * 128 + mt * 16 + q * 4 + r;
            if (slot2 < n_e) {
                int t   = tok[(size_t)e * TT + slot2];
                float wt = wl[(size_t)e * TT + slot2];
                atomicAdd(&outf[(size_t)t * HD + col], wt * acc[mt][r]);
            }
        }
    }
}

extern "C" void kernel_launch(void* const* d_in, const int* in_sizes, int n_in,
                              void* d_out, int out_size, void* d_ws, size_t ws_size,
                              hipStream_t stream) {
    const float* x    = (const float*)d_in[0];
    const float* gw   = (const float*)d_in[1];
    const float* bias = (const float*)d_in[2];
    const float* Wg   = (const float*)d_in[3];
    const float* Wu   = (const float*)d_in[4];
    const float* Wd   = (const float*)d_in[5];
    float* out = (float*)d_out;   // reference output dtype is float32

    char* ws = (char*)d_ws;
    int*      cnt = (int*)(ws + WS_CNT);
    int*      tok = (int*)(ws + WS_TOK);
    float*    wl  = (float*)(ws + WS_WL);
    _Float16* Xe  = (_Float16*)(ws + WS_XE);
    _Float16* A   = (_Float16*)(ws + WS_A);

    hipMemsetAsync(ws, 0, 256, stream);                       // expert counters
    hipMemsetAsync(out, 0, (size_t)TT * HD * 4, stream);      // f32 output accumulator

    k_route<<<TT, 256, 0, stream>>>(x, gw, bias, cnt, tok, wl);
    k_pack<<<NE * NSX, 256, 0, stream>>>(x, cnt, tok, Xe);
    k_gateup<<<NE * 2 * (IDIM / 32), 128, 0, stream>>>(Xe, Wg, Wu, cnt, A);
    k_down<<<NE * 2 * (HD / 32), 128, 0, stream>>>(A, Wd, cnt, tok, wl, out);
}

// Round 4
// 256.599 us; speedup vs baseline: 1.2481x; 1.0771x over previous
//
#include <hip/hip_runtime.h>
#include <cstdint>
#include <cmath>

// Problem constants
constexpr int TT   = 256;   // tokens
constexpr int HD   = 1024;  // hidden
constexpr int IDIM = 512;   // intermediate
constexpr int NE   = 32;    // experts
constexpr int NGRP = 8;
constexpr int TKG  = 4;
constexpr int TOPK = 8;
constexpr float RSCALE = 2.5f;

constexpr int NSX  = HD / 32;     // 32 k-slabs in Xe
constexpr int NSA  = IDIM / 32;   // 16 k-slabs in A
constexpr int SLAB = 16 * 64 * 8; // halves per (expert, slab): 16 mt-tiles x 64 lanes x 8

typedef float    f32x4 __attribute__((ext_vector_type(4)));
typedef _Float16 half8 __attribute__((ext_vector_type(8)));

// Workspace layout (bytes)
constexpr size_t WS_CNT   = 0;                                 // NE ints (zeroed)
constexpr size_t WS_TOK   = 256;                               // NE*TT ints
constexpr size_t WS_WL    = WS_TOK   + (size_t)NE * TT * 4;    // NE*TT floats
constexpr size_t WS_TSLOT = WS_WL    + (size_t)NE * TT * 4;    // TT*TOPK ints
constexpr size_t WS_OFFS  = WS_TSLOT + (size_t)TT * TOPK * 4;  // NE ints (pad 256)
constexpr size_t WS_XE    = WS_OFFS  + 256;                    // 16 MB Xe; Y aliases this after gateup
constexpr size_t WS_A     = WS_XE + (size_t)NE * NSX * SLAB * 2; // 8 MB A
// Y = f32[2048][HD] at WS_XE (8 MB <= 16 MB Xe region, Xe dead after k_gateup)

// global->LDS direct staging, 16B per lane (dest = wave-uniform base + lane*16)
#define GLOAD16(GP, LP) __builtin_amdgcn_global_load_lds(                      \
    (const __attribute__((address_space(1))) unsigned int*)(GP),               \
    (__attribute__((address_space(3))) unsigned int*)(LP), 16, 0, 0)

// counted vmcnt wait; all loop VMEM is global_load_lds (no dest VGPR), so the
// compiler inserts no waits of its own — this is the only vmcnt in the loop.
#define WAITVM(N) asm volatile("s_waitcnt vmcnt(" #N ")" ::: "memory")

// ---------------- Routing ----------------
__global__ __launch_bounds__(256) void k_route(
    const float* __restrict__ x, const float* __restrict__ gw,
    const float* __restrict__ bias, int* __restrict__ cnt,
    int* __restrict__ tok, float* __restrict__ wl, int* __restrict__ tslot)
{
    int t = blockIdx.x;
    int tid = threadIdx.x;
    int e2 = (tid & 15) * 2;
    int c  = tid >> 4;
    const float* xr = x + (size_t)t * HD;

    float a0 = 0.f, a1 = 0.f;
    int h0 = c * (HD / 16);
#pragma unroll 8
    for (int h = h0; h < h0 + HD / 16; ++h) {
        float xv = xr[h];
        float2 wv = *(const float2*)&gw[(size_t)h * NE + e2];
        a0 += xv * wv.x;
        a1 += xv * wv.y;
    }

    __shared__ float part[16][NE];
    part[c][e2]     = a0;
    part[c][e2 + 1] = a1;
    __syncthreads();

    __shared__ float sc[NE], sfc[NE];
    if (tid < NE) {
        float s = 0.f;
#pragma unroll
        for (int cc = 0; cc < 16; ++cc) s += part[cc][tid];
        float sig = 1.f / (1.f + expf(-s));
        sc[tid]  = sig;
        sfc[tid] = sig + bias[tid];
    }
    __syncthreads();

    if (tid == 0) {
        float gs[NGRP];
        for (int g = 0; g < NGRP; ++g) {
            float m1 = -3.0e38f, m2 = -3.0e38f;
            for (int j = 0; j < 4; ++j) {
                float v = sfc[4 * g + j];
                if (v > m1) { m2 = m1; m1 = v; } else if (v > m2) m2 = v;
            }
            gs[g] = m1 + m2;
        }
        bool gsel[NGRP];
        for (int g = 0; g < NGRP; ++g) gsel[g] = false;
        for (int r = 0; r < TKG; ++r) {
            int bi = -1; float bv = -3.0e38f;
            for (int g = 0; g < NGRP; ++g)
                if (!gsel[g] && gs[g] > bv) { bv = gs[g]; bi = g; }
            gsel[bi] = true;
        }
        float masked[NE];
        for (int i = 0; i < NE; ++i) masked[i] = gsel[i >> 2] ? sfc[i] : 0.0f;
        int   idx[TOPK]; float wv[TOPK]; float wsum = 0.f;
        for (int r = 0; r < TOPK; ++r) {
            int bi = -1; float bv = -3.0e38f;
            for (int i = 0; i < NE; ++i)
                if (masked[i] > bv) { bv = masked[i]; bi = i; }
            masked[bi] = -3.0e38f;
            idx[r] = bi; wv[r] = sc[bi]; wsum += wv[r];
        }
        float inv = RSCALE / (wsum + 1e-20f);
        for (int r = 0; r < TOPK; ++r) {
            int ee = idx[r];
            int pos = atomicAdd(&cnt[ee], 1);
            tok[(size_t)ee * TT + pos] = t;
            wl [(size_t)ee * TT + pos] = wv[r] * inv;
            tslot[t * TOPK + r] = ee * TT + pos;
        }
    }
}

// ---------------- Prefix offsets over expert counts ----------------
__global__ __launch_bounds__(64) void k_offs(const int* __restrict__ cnt,
                                             int* __restrict__ offs)
{
    if (threadIdx.x == 0) {
        int s = 0;
        for (int e = 0; e < NE; ++e) { offs[e] = s; s += cnt[e]; }
    }
}

// ---------------- Pack: gather x rows into MFMA-A-fragment slabs ----------------
__global__ __launch_bounds__(256) void k_pack(
    const float* __restrict__ x, const int* __restrict__ cnt,
    const int* __restrict__ tok, _Float16* __restrict__ Xe)
{
    int bid  = blockIdx.x;
    int xcd  = bid & 7;
    int slot = bid >> 3;            // 0..127
    int e    = xcd * 4 + (slot & 3);
    int s    = slot >> 2;           // 0..31
    int n_e = cnt[e];
    if (n_e == 0) return;
    int tid = threadIdx.x, w = tid >> 6, lane = tid & 63;
    int m16 = lane & 15, q = lane >> 4;
    _Float16* base = Xe + ((size_t)e * NSX + s) * SLAB;
#pragma unroll
    for (int k = 0; k < 4; ++k) {
        int mt = w + k * 4;
        int slot2 = mt * 16 + m16;
        if (slot2 >= n_e) slot2 = n_e - 1;   // clamp: dup of last row (finite garbage)
        int t = tok[e * TT + slot2];
        const float* src = x + (size_t)t * HD + s * 32 + q * 8;
        f32x4 v0 = *(const f32x4*)src;
        f32x4 v1 = *(const f32x4*)(src + 4);
        half8 h;
        h[0] = (_Float16)v0.x; h[1] = (_Float16)v0.y; h[2] = (_Float16)v0.z; h[3] = (_Float16)v0.w;
        h[4] = (_Float16)v1.x; h[5] = (_Float16)v1.y; h[6] = (_Float16)v1.z; h[7] = (_Float16)v1.w;
        *(half8*)(base + ((size_t)mt * 64 + lane) * 8) = h;
    }
}

// ---------------- Gate/Up ----------------
// 1024 blocks (XCD-swizzled), 128 threads = 2 waves; tile 128 tokens x 32 cols.
// ALL loop VMEM is global_load_lds (weights from HBM, A-tile from L2-resident
// Xe) into 5 LDS buffers staged 3 ahead; fragments come back via ds_read
// (conflict-free b128 for A, 2-way-free b32 for weights). Raw s_barrier +
// counted vmcnt (steady 24 = 3 steps x 8 gloads/wave). No register global
// loads in the loop -> compiler inserts no vmcnt of its own.
__global__ __launch_bounds__(128, 1) void k_gateup(
    const _Float16* __restrict__ Xe, const float* __restrict__ Wg,
    const float* __restrict__ Wu, const int* __restrict__ cnt,
    _Float16* __restrict__ A)
{
    int bid  = blockIdx.x;
    int xcd  = bid & 7;
    int slot = bid >> 3;            // 0..127
    int e    = xcd * 4 + (slot & 3);
    int rest = slot >> 2;           // 0..31
    int ttile = rest & 1;
    int ig    = rest >> 1;          // 0..15 (32-col groups)
    int n_e = cnt[e];
    if (ttile * 128 >= n_e) return;
    int mtbase = ttile * 8;
    int i0 = ig * 32;
    int tid  = threadIdx.x;
    int w    = tid >> 6;            // wave 0/1 -> cols i0 + w*16 .. +15
    int lane = tid & 63;
    int m16 = lane & 15, q = lane >> 4;
    int wcol = w * 16 + m16;

    __shared__ __align__(16) float    LG[5][32][32];   // 20 KB
    __shared__ __align__(16) float    LU[5][32][32];   // 20 KB
    __shared__ __align__(16) _Float16 LA[5][4096];     // 40 KB

    const _Float16* aslab = Xe + (size_t)e * NSX * SLAB + (size_t)mtbase * 512;
    const float* gw0 = Wg + (size_t)e * HD * IDIM + i0;
    const float* uw0 = Wu + (size_t)e * HD * IDIM + i0;

    f32x4 accG[8], accU[8];
#pragma unroll
    for (int mt = 0; mt < 8; ++mt) {
        accG[mt] = (f32x4){0.f, 0.f, 0.f, 0.f};
        accU[mt] = (f32x4){0.f, 0.f, 0.f, 0.f};
    }

    // stage step KS into buffer B: 8 gloads/wave (4 weights + 4 A-tile).
    // weight content swizzle: LDS[row][col] = W[row][col ^ (((row>>3)&1)<<4)].
#define GU_STAGE(B, KS)                                                        \
    { _Pragma("unroll")                                                        \
      for (int ci = 0; ci < 2; ++ci) {                                         \
        int c    = w * 2 + ci;                                                 \
        int row  = c * 8 + (lane >> 3);                                        \
        int csrc = ((lane & 7) << 2) ^ ((c & 1) << 4);                         \
        const float* gs = gw0 + ((size_t)(KS) * 32 + row) * IDIM + csrc;       \
        const float* us = uw0 + ((size_t)(KS) * 32 + row) * IDIM + csrc;       \
        GLOAD16(gs, &LG[B][c * 8][0]);                                         \
        GLOAD16(us, &LU[B][c * 8][0]);                                         \
      }                                                                        \
      _Pragma("unroll")                                                        \
      for (int i_ = 0; i_ < 4; ++i_) {                                         \
        int off_ = (w * 4 + i_) * 512;                                         \
        const _Float16* as_ = aslab + (size_t)(KS) * SLAB + off_ + lane * 8;   \
        GLOAD16(as_, &LA[B][off_]);                                            \
      } }

    // fragment reads: A via ds_read_b128 (contiguous 1KB/instr, conflict-free);
    // weights: lane (m16,q) needs W[k=q*8+j][wcol] at stored col wcol^((q&1)<<4)
    // -> 2-way banks (free).
#define GU_COMPUTE(B)                                                          \
    { int lc = wcol ^ ((q & 1) << 4);                                          \
      half8 bg, bu;                                                            \
      _Pragma("unroll")                                                        \
      for (int j_ = 0; j_ < 8; ++j_) {                                         \
        bg[j_] = (_Float16)LG[B][q * 8 + j_][lc];                              \
        bu[j_] = (_Float16)LU[B][q * 8 + j_][lc];                              \
      }                                                                        \
      _Pragma("unroll")                                                        \
      for (int mt_ = 0; mt_ < 8; ++mt_) {                                      \
        half8 afr = *(const half8*)&LA[B][mt_ * 512 + lane * 8];               \
        accG[mt_] = __builtin_amdgcn_mfma_f32_16x16x32_f16(afr, bg, accG[mt_], 0, 0, 0); \
        accU[mt_] = __builtin_amdgcn_mfma_f32_16x16x32_f16(afr, bu, accU[mt_], 0, 0, 0); \
      } }

    constexpr int NK = HD / 32;   // 32
    GU_STAGE(0, 0) GU_STAGE(1, 1) GU_STAGE(2, 2)

#pragma unroll
    for (int ks = 0; ks < NK; ++ks) {
        if (ks + 3 < NK) GU_STAGE((ks + 3) % 5, ks + 3)
        if      (ks + 4 <= NK) { WAITVM(24); }
        else if (ks + 3 == NK) { WAITVM(16); }
        else if (ks + 2 == NK) { WAITVM(8);  }
        else                   { WAITVM(0);  }
        __builtin_amdgcn_s_barrier();
        __builtin_amdgcn_sched_barrier(0);
        GU_COMPUTE(ks % 5)
    }
#undef GU_STAGE
#undef GU_COMPUTE

    // store silu(g)*u into A in A-fragment slab order (for k_down's A-operand)
    int iyw = ig * 2 + w;                       // 16-col tile index 0..31
    _Float16* aout = A + ((size_t)e * NSA + (iyw >> 1)) * SLAB;
    int cj   = m16 & 7;
    int lsub = ((iyw * 2 + (m16 >> 3)) & 3) * 16;
#pragma unroll
    for (int mt = 0; mt < 8; ++mt) {
#pragma unroll
        for (int r = 0; r < 4; ++r) {
            float g = accG[mt][r], u = accU[mt][r];
            float a = (g / (1.f + expf(-g))) * u;
            int lp = (q * 4 + r) + lsub;
            aout[((size_t)(mtbase + mt) * 64 + lp) * 8 + cj] = (_Float16)a;
        }
    }
}

// ---------------- Down ----------------
// 2048 blocks (XCD-swizzled), 128 threads = 2 waves; tile 128 tokens x 32 cols.
// Same pure-gload_lds pipeline (6 gloads/wave/step). Output: weighted partials
// to compact Y[slot][HD] (no atomics); k_combine sums per token.
__global__ __launch_bounds__(128, 1) void k_down(
    const _Float16* __restrict__ A, const float* __restrict__ Wd,
    const int* __restrict__ cnt, const int* __restrict__ offs,
    const float* __restrict__ wl, float* __restrict__ Y)
{
    int bid  = blockIdx.x;
    int xcd  = bid & 7;
    int slot = bid >> 3;            // 0..255
    int e    = xcd * 4 + (slot & 3);
    int rest = slot >> 2;           // 0..63
    int ttile = rest & 1;
    int hg    = rest >> 1;          // 0..31 (32-col groups)
    int n_e = cnt[e];
    if (ttile * 128 >= n_e) return;
    int mtbase = ttile * 8;
    int h0 = hg * 32;
    int tid  = threadIdx.x;
    int w    = tid >> 6;
    int lane = tid & 63;
    int m16 = lane & 15, q = lane >> 4;
    int wcol = w * 16 + m16;

    __shared__ __align__(16) float    LD[5][32][32];   // 20 KB
    __shared__ __align__(16) _Float16 LA[5][4096];     // 40 KB

    const _Float16* aslab = A + (size_t)e * NSA * SLAB + (size_t)mtbase * 512;
    const float* dw0 = Wd + (size_t)e * IDIM * HD + h0;

    f32x4 acc[8];
#pragma unroll
    for (int mt = 0; mt < 8; ++mt) acc[mt] = (f32x4){0.f, 0.f, 0.f, 0.f};

#define DN_STAGE(B, KS)                                                        \
    { _Pragma("unroll")                                                        \
      for (int ci = 0; ci < 2; ++ci) {                                         \
        int c    = w * 2 + ci;                                                 \
        int row  = c * 8 + (lane >> 3);                                        \
        int csrc = ((lane & 7) << 2) ^ ((c & 1) << 4);                         \
        const float* ds = dw0 + ((size_t)(KS) * 32 + row) * HD + csrc;         \
        GLOAD16(ds, &LD[B][c * 8][0]);                                         \
      }                                                                        \
      _Pragma("unroll")                                                        \
      for (int i_ = 0; i_ < 4; ++i_) {                                         \
        int off_ = (w * 4 + i_) * 512;                                         \
        const _Float16* as_ = aslab + (size_t)(KS) * SLAB + off_ + lane * 8;   \
        GLOAD16(as_, &LA[B][off_]);                                            \
      } }

#define DN_COMPUTE(B)                                                          \
    { int lc = wcol ^ ((q & 1) << 4);                                          \
      half8 bd;                                                                \
      _Pragma("unroll")                                                        \
      for (int j_ = 0; j_ < 8; ++j_) bd[j_] = (_Float16)LD[B][q * 8 + j_][lc]; \
      _Pragma("unroll")                                                        \
      for (int mt_ = 0; mt_ < 8; ++mt_) {                                      \
        half8 afr = *(const half8*)&LA[B][mt_ * 512 + lane * 8];               \
        acc[mt_] = __builtin_amdgcn_mfma_f32_16x16x32_f16(afr, bd, acc[mt_], 0, 0, 0); \
      } }

    constexpr int NK = IDIM / 32;  // 16
    DN_STAGE(0, 0) DN_STAGE(1, 1) DN_STAGE(2, 2)

#pragma unroll
    for (int ks = 0; ks < NK; ++ks) {
        if (ks + 3 < NK) DN_STAGE((ks + 3) % 5, ks + 3)
        if      (ks + 4 <= NK) { WAITVM(18); }
        else if (ks + 3 == NK) { WAITVM(12); }
        else if (ks + 2 == NK) { WAITVM(6);  }
        else                   { WAITVM(0);  }
        __builtin_amdgcn_s_barrier();
        __builtin_amdgcn_sched_barrier(0);
        DN_COMPUTE(ks % 5)
    }
#undef DN_STAGE
#undef DN_COMPUTE

    int oe = offs[e];
    int col = h0 + w * 16 + m16;
#pragma unroll
    for (int mt = 0; mt < 8; ++mt) {
#pragma unroll
        for (int r = 0; r < 4; ++r) {
            int slot2 = ttile * 128 + mt * 16 + q * 4 + r;
            if (slot2 < n_e) {
                float wt = wl[(size_t)e * TT + slot2];
                Y[(size_t)(oe + slot2) * HD + col] = wt * acc[mt][r];
            }
        }
    }
}

// ---------------- Combine: out[t] = sum of the token's 8 weighted partials ----
__global__ __launch_bounds__(256) void k_combine(
    const float* __restrict__ Y, const int* __restrict__ tslot,
    const int* __restrict__ offs, float* __restrict__ out)
{
    int t = blockIdx.x, tid = threadIdx.x;
    f32x4 s = (f32x4){0.f, 0.f, 0.f, 0.f};
#pragma unroll
    for (int r = 0; r < TOPK; ++r) {
        int ts  = tslot[t * TOPK + r];
        int e   = ts >> 8;            // TT = 256
        int pos = ts & 255;
        const float* yp = Y + (size_t)(offs[e] + pos) * HD + tid * 4;
        f32x4 v = *(const f32x4*)yp;
        s.x += v.x; s.y += v.y; s.z += v.z; s.w += v.w;
    }
    *(f32x4*)&out[(size_t)t * HD + tid * 4] = s;
}

extern "C" void kernel_launch(void* const* d_in, const int* in_sizes, int n_in,
                              void* d_out, int out_size, void* d_ws, size_t ws_size,
                              hipStream_t stream) {
    const float* x    = (const float*)d_in[0];
    const float* gw   = (const float*)d_in[1];
    const float* bias = (const float*)d_in[2];
    const float* Wg   = (const float*)d_in[3];
    const float* Wu   = (const float*)d_in[4];
    const float* Wd   = (const float*)d_in[5];
    float* out = (float*)d_out;   // reference output dtype is float32

    char* ws = (char*)d_ws;
    int*      cnt   = (int*)(ws + WS_CNT);
    int*      tok   = (int*)(ws + WS_TOK);
    float*    wl    = (float*)(ws + WS_WL);
    int*      tslot = (int*)(ws + WS_TSLOT);
    int*      offs  = (int*)(ws + WS_OFFS);
    _Float16* Xe    = (_Float16*)(ws + WS_XE);
    _Float16* A     = (_Float16*)(ws + WS_A);
    float*    Y     = (float*)(ws + WS_XE);   // aliases Xe (dead after k_gateup)

    hipMemsetAsync(ws, 0, 256, stream);       // expert counters

    k_route<<<TT, 256, 0, stream>>>(x, gw, bias, cnt, tok, wl, tslot);
    k_offs<<<1, 64, 0, stream>>>(cnt, offs);
    k_pack<<<NE * NSX, 256, 0, stream>>>(x, cnt, tok, Xe);
    k_gateup<<<NE * 2 * (IDIM / 32), 128, 0, stream>>>(Xe, Wg, Wu, cnt, A);
    k_down<<<NE * 2 * (HD / 32), 128, 0, stream>>>(A, Wd, cnt, offs, wl, Y);
    k_combine<<<TT, 256, 0, stream>>>(Y, tslot, offs, out);
}